// Round 21
// baseline (281.189 us; speedup 1.0000x reference)
//
#include <hip/hip_runtime.h>
#include <hip/hip_bf16.h>

#define NROWS 131072
#define DDIM  64
#define KCODES 1024
#define HW    4096

// d_out is FLOAT32. Element offsets (reference return order):
#define OFF_ZQ   0ull
#define OFF_IDX  8388608ull
#define OFF_LOSS 8519680ull
#define OFF_EMB  8519681ull
#define OFF_NCS  8585217ull
#define OFF_EAVG 8586241ull

// d_out tail scratch (overlays emb/ncs outputs; consumed then rewritten):
#define SCR_B0    34078724ull
#define SCR_WLO   (SCR_B0 + 131072ull)
#define SCR_W2O   (SCR_B0 + 262144ull)
#define LCAP      20480u

// ---- fast-path ws layout (17,547,272 B <= proven 17,563,648) ----
#define FWS_KSCR   16777216ull
#define FWS_SCS    17047556ull
#define FWS_LIST   17301504ull
#define FWS_RMIN   17383424ull
#define FWS_CNTR   17547264ull
#define FWS_LOSSA  17547268ull
#define FWS_TOTAL  17547272ull

// ---- fallback (round-11 verbatim) ws layout ----
#define WSO_KSCR   262144ull
#define WSO_LOSSB  786432ull
#define WSO_SMOOTH 788480ull
#define WSO_CNT    792576ull
#define WSO_ESUM   858112ull

#define GAPTHR 8e-5f

typedef __attribute__((ext_vector_type(8))) short bf16x8;
typedef __attribute__((ext_vector_type(4))) float f32x4;

#define GLOAD_LDS16(gp, lp)                                                     \
    __builtin_amdgcn_global_load_lds(                                           \
        (const __attribute__((address_space(1))) void*)(gp),                    \
        (__attribute__((address_space(3))) void*)(lp), 16, 0, 0)

__device__ __forceinline__ float np_sumsq64(const float* v) {
#pragma clang fp contract(off)
    float r0 = v[0]*v[0], r1 = v[1]*v[1], r2 = v[2]*v[2], r3 = v[3]*v[3];
    float r4 = v[4]*v[4], r5 = v[5]*v[5], r6 = v[6]*v[6], r7 = v[7]*v[7];
    for (int i = 8; i < 64; i += 8) {
        r0 += v[i+0]*v[i+0]; r1 += v[i+1]*v[i+1];
        r2 += v[i+2]*v[i+2]; r3 += v[i+3]*v[i+3];
        r4 += v[i+4]*v[i+4]; r5 += v[i+5]*v[i+5];
        r6 += v[i+6]*v[i+6]; r7 += v[i+7]*v[i+7];
    }
    return ((r0+r1)+(r2+r3))+((r4+r5)+(r6+r7));
}
__device__ __forceinline__ float mul_rn(float a, float b) {
#pragma clang fp contract(off)
    return a * b;
}
__device__ __forceinline__ float add_rn(float a, float b) {
#pragma clang fp contract(off)
    return a + b;
}
__device__ __forceinline__ float sub2_rn(float s, float a) {
#pragma clang fp contract(off)
    return s - 2.0f * a;
}
__device__ __forceinline__ unsigned bf16rne(float v) {
    unsigned b = __float_as_uint(v);
    return (b + 0x7FFFu + ((b >> 16) & 1u)) >> 16;
}
__device__ __forceinline__ float bfu2f(unsigned short u) {
    return __uint_as_float(((unsigned)u) << 16);
}
__device__ __forceinline__ unsigned flipf(float v) {
    unsigned b = __float_as_uint(v);
    return b ^ (0x80000000u | (unsigned)((int)b >> 31));
}
__device__ __forceinline__ float unflip_val(unsigned u) {
    u &= 0xFFFFFC00u;
    unsigned mask = 0x80000000u | (unsigned)((int)(~u) >> 31);
    return __uint_as_float(u ^ mask);
}

__global__ __launch_bounds__(256) void prep_kernel(
        const float* __restrict__ emb, const float* __restrict__ cs,
        unsigned short* __restrict__ wh, unsigned short* __restrict__ wl,
        float* __restrict__ w2, float* __restrict__ embT,
        float* __restrict__ scs) {
    __shared__ float tile[64][65];
    __shared__ float sred[4];
    const int t = threadIdx.x;
    const int kb = blockIdx.x * 64;
#pragma unroll
    for (int i = 0; i < 16; ++i) {
        const int e = t + i * 256;
        const int kl = e >> 6, d = e & 63;
        const float v = emb[(size_t)(kb + kl) * DDIM + d];
        tile[kl][d] = v;
        const unsigned rh = bf16rne(v);
        const float lv = v - bfu2f((unsigned short)rh);
        wh[(size_t)(kb + kl) * DDIM + d] = (unsigned short)rh;
        wl[(size_t)(kb + kl) * DDIM + d] = (unsigned short)bf16rne(lv);
    }
    __syncthreads();
    if (t < 64) w2[kb + t] = np_sumsq64(&tile[t][0]);
#pragma unroll
    for (int i = 0; i < 16; ++i) {
        const int e = t + i * 256;
        const int d = e >> 6, kl = e & 63;
        embT[(size_t)d * KCODES + kb + kl] = tile[kl][d];
    }
    if (blockIdx.x == 0) {
        float v = cs[t * 4] + cs[t * 4 + 1] + cs[t * 4 + 2] + cs[t * 4 + 3];
#pragma unroll
        for (int off = 32; off > 0; off >>= 1) v += __shfl_down(v, off, 64);
        if ((t & 63) == 0) sred[t >> 6] = v;
        __syncthreads();
        if (t == 0) scs[0] = sred[0] + sred[1] + sred[2] + sred[3];
    }
}

#define CBLOAD(S, c)                                                          \
    { const size_t a_ = ((size_t)(((c) * 16 + col) * DDIM + grp * 8));        \
      wh##S##0 = *(const bf16x8*)(wh + a_);                                   \
      wh##S##1 = *(const bf16x8*)(wh + a_ + 32);                              \
      wl##S##0 = *(const bf16x8*)(wl + a_);                                   \
      wl##S##1 = *(const bf16x8*)(wl + a_ + 32); }

// score2: 256-row tile (grid 512, 2 blocks/CU). MFMA top-2 + xT dump + idx
// + z_q + flagged-list append; LDS codebook double-buffer + w2 in LDS.
__global__ __launch_bounds__(512, 2) void score2_kernel(
        const float* __restrict__ z, const float* __restrict__ emb,
        const unsigned short* __restrict__ wh, const unsigned short* __restrict__ wl,
        const float* __restrict__ w2g, float* __restrict__ out,
        unsigned short* __restrict__ xT, unsigned* __restrict__ list,
        unsigned long long* __restrict__ rmin, unsigned* __restrict__ counter) {
    __shared__ __attribute__((aligned(16))) unsigned short sxt[64][256];
    __shared__ __attribute__((aligned(16))) unsigned short cb[2][2][4][512];
    __shared__ float w2s[KCODES];
    __shared__ unsigned k1s[256];

    const int tid = threadIdx.x;
    const int lane = tid & 63, wid = tid >> 6;
    const int col = lane & 15, grp = lane >> 4;
    const int nb = blockIdx.x * 256;
    const int b = nb >> 12, hb = (nb >> 6) & 63;
    const int w4 = (lane & 15) * 4, h4 = lane >> 4;   // 4 h x 64 w per wave-lane map

    for (int i = tid; i < KCODES; i += 512) w2s[i] = w2g[i];

    // stage 256 rows of x into LDS (transposed, bf16-hi) — r16-proven map
    {
        const int row = h4 * 64 + w4;
#pragma unroll
        for (int it = 0; it < 8; ++it) {
            const int d = wid + 8 * it;
            const float4 v = *(const float4*)&z[((size_t)(b * 64 + d)) * HW + (hb + h4) * 64 + w4];
            ushort4 u;
            u.x = (unsigned short)bf16rne(v.x);
            u.y = (unsigned short)bf16rne(v.y);
            u.z = (unsigned short)bf16rne(v.z);
            u.w = (unsigned short)bf16rne(v.w);
            *(ushort4*)&sxt[d][row] = u;
        }
    }
    __syncthreads();

    // fragments (wave owns 32 rows) + xT dump straight from fragments
    bf16x8 fx[2][2];
#pragma unroll
    for (int rt = 0; rt < 2; ++rt)
#pragma unroll
        for (int kh = 0; kh < 2; ++kh) {
            const int row = wid * 32 + rt * 16 + col;
            bf16x8 f;
#pragma unroll
            for (int j = 0; j < 8; ++j)
                f[j] = (short)sxt[kh * 32 + grp * 8 + j][row];
            fx[rt][kh] = f;
            *(bf16x8*)&xT[(size_t)(nb + row) * DDIM + kh * 32 + grp * 8] = f;
        }

    // codebook staging (r9-proven geometry): 1KB per wave per round
    const int pr = wid >> 2, sW = (wid >> 1) & 1, khW = wid & 1;
    const unsigned short* gsrc = (pr ? wl : wh) + khW * 32 + grp * 8
                               + (size_t)(sW * 16 + col) * DDIM;

    GLOAD_LDS16(gsrc, &cb[0][pr][sW * 2 + khW][0]);
    asm volatile("s_waitcnt vmcnt(0)" ::: "memory");
    __builtin_amdgcn_s_barrier();

    unsigned m1[2] = {~0u, ~0u}, m2[2] = {~0u, ~0u};

    for (int rd = 0; rd < 32; ++rd) {
        const int cur = rd & 1;
        if (rd < 31)
            GLOAD_LDS16(gsrc + (size_t)(rd + 1) * 32 * DDIM,
                        &cb[cur ^ 1][pr][sW * 2 + khW][0]);
#pragma unroll
        for (int s = 0; s < 2; ++s) {
            const bf16x8 vh0 = *(const bf16x8*)&cb[cur][0][s * 2 + 0][lane * 8];
            const bf16x8 vh1 = *(const bf16x8*)&cb[cur][0][s * 2 + 1][lane * 8];
            const bf16x8 vl0 = *(const bf16x8*)&cb[cur][1][s * 2 + 0][lane * 8];
            const bf16x8 vl1 = *(const bf16x8*)&cb[cur][1][s * 2 + 1][lane * 8];
            const int c = rd * 2 + s;
            const float4 w2v = *(const float4*)&w2s[c * 16 + grp * 4];
            const float* w2p = (const float*)&w2v;
#pragma unroll
            for (int rt = 0; rt < 2; ++rt) {
                f32x4 a = {0.f, 0.f, 0.f, 0.f};
                a = __builtin_amdgcn_mfma_f32_16x16x32_bf16(vh0, fx[rt][0], a, 0, 0, 0);
                a = __builtin_amdgcn_mfma_f32_16x16x32_bf16(vl0, fx[rt][0], a, 0, 0, 0);
                a = __builtin_amdgcn_mfma_f32_16x16x32_bf16(vh1, fx[rt][1], a, 0, 0, 0);
                a = __builtin_amdgcn_mfma_f32_16x16x32_bf16(vl1, fx[rt][1], a, 0, 0, 0);
#pragma unroll
                for (int r = 0; r < 4; ++r) {
                    const float val = fmaf(-2.f, a[r], w2p[r]);
                    const unsigned u = (flipf(val) & 0xFFFFFC00u) |
                                       (unsigned)(c * 16 + grp * 4 + r);
                    const unsigned mx = m1[rt] > u ? m1[rt] : u;
                    m1[rt] = m1[rt] < u ? m1[rt] : u;
                    m2[rt] = m2[rt] < mx ? m2[rt] : mx;
                }
            }
        }
        asm volatile("s_waitcnt vmcnt(0) lgkmcnt(0)" ::: "memory");
        __builtin_amdgcn_s_barrier();
    }

    // merge top-2 across the 4 grp-lanes sharing each row
#pragma unroll
    for (int rt = 0; rt < 2; ++rt) {
        for (int off = 16; off <= 32; off <<= 1) {
            const unsigned o1 = (unsigned)__shfl_xor((int)m1[rt], off, 64);
            const unsigned o2 = (unsigned)__shfl_xor((int)m2[rt], off, 64);
            const unsigned mx = m1[rt] > o1 ? m1[rt] : o1;
            m1[rt] = m1[rt] < o1 ? m1[rt] : o1;
            const unsigned t2 = m2[rt] < o2 ? m2[rt] : o2;
            m2[rt] = t2 < mx ? t2 : mx;
        }
    }

    bool flag[2];
    unsigned long long mrt[2];
    unsigned wavecnt = 0;
#pragma unroll
    for (int rt = 0; rt < 2; ++rt) {
        flag[rt] = (grp == 0) &&
                   ((unflip_val(m2[rt]) - unflip_val(m1[rt])) < GAPTHR);
        mrt[rt] = __ballot(flag[rt]);
        wavecnt += (unsigned)__popcll(mrt[rt]);
    }

    // provisional idx + k1s (fix_kernel rewrites flagged entries later)
    if (grp == 0) {
#pragma unroll
        for (int rt = 0; rt < 2; ++rt) {
            const unsigned k = m1[rt] & 1023u;
            out[OFF_IDX + (size_t)(nb + wid * 32 + rt * 16 + col)] = (float)k;
            k1s[wid * 32 + rt * 16 + col] = k;
        }
    }

    // dense list append: one atomic per wave
    unsigned base = 0;
    if (lane == 0 && wavecnt) base = atomicAdd(counter, wavecnt);
    base = (unsigned)__shfl((int)base, 0, 64);
    unsigned offrt = 0;
#pragma unroll
    for (int rt = 0; rt < 2; ++rt) {
        if (flag[rt]) {
            const unsigned offin =
                (unsigned)__popcll(mrt[rt] & ((lane == 0) ? 0ull : (~0ull >> (64 - lane))));
            const unsigned slot = base + offrt + offin;
            if (slot < LCAP) {
                list[slot] = (unsigned)(nb + wid * 32 + rt * 16 + col);
                rmin[slot] = ~0ull;
            }
        }
        offrt += (unsigned)__popcll(mrt[rt]);
    }

    // fused z_q write (provisional; fix rewrites flagged rows)
    __syncthreads();
    {
        const int r0 = h4 * 64 + w4;
        const float* e0 = emb + (size_t)k1s[r0 + 0] * DDIM;
        const float* e1 = emb + (size_t)k1s[r0 + 1] * DDIM;
        const float* e2 = emb + (size_t)k1s[r0 + 2] * DDIM;
        const float* e3 = emb + (size_t)k1s[r0 + 3] * DDIM;
#pragma unroll
        for (int it = 0; it < 8; ++it) {
            const int d = wid + 8 * it;
            float4 q;
            q.x = e0[d]; q.y = e1[d]; q.z = e2[d]; q.w = e3[d];
            *(float4*)&out[((size_t)(b * 64 + d)) * HW + (hb + h4) * 64 + w4] = q;
        }
    }
}

// rescan_b: batched np-exact rescan. lane = flagged row; K split 8 ways.
__global__ __launch_bounds__(256, 1) void rescanb_kernel(
        const float* __restrict__ z, const float* __restrict__ emb,
        const float* __restrict__ w2, const unsigned* __restrict__ list,
        const unsigned* __restrict__ counter,
        unsigned long long* __restrict__ rmin) {
    const int lane = threadIdx.x & 63;
    const int wid = __builtin_amdgcn_readfirstlane(threadIdx.x >> 6);
    unsigned cnt = __builtin_amdgcn_readfirstlane(*counter);
    if (cnt > LCAP) cnt = LCAP;
    if (cnt == 0) return;
    const unsigned W = ((cnt + 63) >> 6) * 8;

    for (unsigned w = blockIdx.x * 4 + wid; w < W; w += gridDim.x * 4) {
        const unsigned g = w >> 3, p = w & 7;
        const unsigned slot = g * 64 + lane;
        const bool valid = slot < cnt;
        const unsigned n = list[valid ? slot : 0];
        const unsigned hw = n & 4095u, bb = n >> 12;

        float x[64];
#pragma unroll
        for (int d = 0; d < 64; ++d)
            x[d] = z[(size_t)(bb * 64 + d) * (size_t)HW + hw];

        float r[8];
#pragma unroll
        for (int j = 0; j < 8; ++j) r[j] = mul_rn(x[j], x[j]);
#pragma unroll
        for (int i = 8; i < 64; i += 8)
#pragma unroll
            for (int j = 0; j < 8; ++j)
                r[j] = add_rn(r[j], mul_rn(x[i + j], x[i + j]));
        const float x2 = add_rn(add_rn(add_rn(r[0], r[1]), add_rn(r[2], r[3])),
                                add_rn(add_rn(r[4], r[5]), add_rn(r[6], r[7])));

        unsigned long long best = ~0ull;
        const int k0 = (int)p * 128;
        for (int k = k0; k < k0 + 128; k += 2) {
            const float* wa = emb + (size_t)k * DDIM;
            const float* wb = wa + DDIM;
            float aa = 0.f, ab = 0.f;
#pragma unroll
            for (int d = 0; d < 64; ++d) {
                aa = fmaf(x[d], wa[d], aa);   // np seq-fma, d ascending
                ab = fmaf(x[d], wb[d], ab);
            }
            const float da = sub2_rn(add_rn(x2, w2[k]),     aa);
            const float db = sub2_rn(add_rn(x2, w2[k + 1]), ab);
            const unsigned long long ua =
                ((unsigned long long)flipf(da) << 10) | (unsigned long long)k;
            const unsigned long long ub =
                ((unsigned long long)flipf(db) << 10) | (unsigned long long)(k + 1);
            best = best < ua ? best : ua;
            best = best < ub ? best : ub;
        }
        if (valid) atomicMin(&rmin[slot], best);
    }
}

// fix: rewrite idx AND z_q for flagged rows (lane = d)
__global__ __launch_bounds__(256) void fix_kernel(
        const unsigned* __restrict__ list, const unsigned long long* __restrict__ rmin,
        const unsigned* __restrict__ counter, const float* __restrict__ emb,
        float* __restrict__ out) {
    unsigned cnt = *counter;
    if (cnt > LCAP) cnt = LCAP;
    const int lane = threadIdx.x & 63, ws = threadIdx.x >> 6;
    const unsigned t = blockIdx.x * 4 + ws;
    if (t >= cnt) return;
    const unsigned long long u = rmin[t];
    if (u == ~0ull) return;
    const unsigned k = (unsigned)(u & 1023ull);
    const unsigned n = list[t];
    if (lane == 0) out[OFF_IDX + (size_t)n] = (float)k;
    const unsigned hw = n & 4095u, bb = n >> 12;
    out[((size_t)(bb * 64 + lane)) * HW + hw] = emb[(size_t)k * DDIM + lane];
}

// gatherfin: 1 block/code; scan idx + gather xT; finalize ncs/eavg/emb + loss
__global__ __launch_bounds__(256) void gatherfin_kernel(
        const float* __restrict__ idxf, const unsigned short* __restrict__ xT,
        const float* __restrict__ emb, const float* __restrict__ cs,
        const float* __restrict__ eavg, const float* __restrict__ w2,
        const float* __restrict__ scs, float* __restrict__ out,
        float* __restrict__ lossA) {
    const int k = blockIdx.x;
    const int lane = threadIdx.x & 63, wid = threadIdx.x >> 6;
    const float fk = (float)k;
    float acc = 0.f, s2 = 0.f;
    unsigned cnt = 0;
    const int wbase = wid * 32768;

    float4 cur = *(const float4*)&idxf[wbase + lane * 4];
    for (int it = 0; it < 128; ++it) {
        float4 nxt;
        if (it + 1 < 128)
            nxt = *(const float4*)&idxf[wbase + (it + 1) * 256 + lane * 4];
        const float* cp = (const float*)&cur;
#pragma unroll
        for (int j = 0; j < 4; ++j) {
            unsigned long long m = __ballot(cp[j] == fk);
            cnt += (unsigned)__popcll(m);
            while (m) {
                const int src = __ffsll(m) - 1;
                m &= m - 1;
                const int n = wbase + it * 256 + src * 4 + j;
                const float xv = bfu2f(xT[(size_t)n * DDIM + lane]);
                acc += xv;
                s2 = fmaf(xv, xv, s2);
            }
        }
        cur = nxt;
    }
#pragma unroll
    for (int off = 32; off > 0; off >>= 1) s2 += __shfl_down(s2, off, 64);
    __shared__ float sacc[4][64];
    __shared__ float ssx2[4];
    __shared__ unsigned scnt[4];
    sacc[wid][lane] = acc;
    if (lane == 0) { ssx2[wid] = s2; scnt[wid] = cnt; }
    __syncthreads();
    if (wid == 0) {
        const float es = sacc[0][lane] + sacc[1][lane] + sacc[2][lane] + sacc[3][lane];
        const float cntk = (float)(scnt[0] + scnt[1] + scnt[2] + scnt[3]);
        const float sx2 = ssx2[0] + ssx2[1] + ssx2[2] + ssx2[3];
        const float w2k = w2[k];                     // read BEFORE ncs write below
        const float wkd = emb[(size_t)k * DDIM + lane];

        float dt = es * wkd;
#pragma unroll
        for (int off = 32; off > 0; off >>= 1) dt += __shfl_down(dt, off, 64);

        const float ncs = fmaf(0.01f, cntk, 0.99f * cs[k]);
        const float nn  = fmaf(0.99f, scs[0], 1310.72f);   // 0.01 * 131072
        const float smoothed = (ncs + 1e-5f) / (nn + 1024.f * 1e-5f) * nn;

        if (lane == 0) {
            out[OFF_NCS + (size_t)k] = ncs;                 // overlays w2[k]
            atomicAdd(lossA, sx2 - 2.f * dt + cntk * w2k);
        }
        const float ea = fmaf(0.01f, es, 0.99f * eavg[(size_t)k * DDIM + lane]);
        out[OFF_EAVG + (size_t)k * DDIM + lane] = ea;
        out[OFF_EMB  + (size_t)k * DDIM + lane] = ea / smoothed;
    }
}

__global__ __launch_bounds__(64) void lossfin_kernel(
        const float* __restrict__ lossA, float* __restrict__ out) {
    if (threadIdx.x == 0)
        out[OFF_LOSS] = 0.25f * lossA[0] / 8388608.f;
}

// ====================== FALLBACK (round-11 verbatim) ======================

#define CBCOMP(S, c)                                                          \
    { const float4 w2v = *(const float4*)&w2s[(c) * 16 + grp * 4];            \
      const float* w2p = (const float*)&w2v;                                  \
      _Pragma("unroll")                                                       \
      for (int rt = 0; rt < 2; ++rt) {                                        \
        f32x4 aA = {0.f,0.f,0.f,0.f}, aB = {0.f,0.f,0.f,0.f};                 \
        aA = __builtin_amdgcn_mfma_f32_16x16x32_bf16(wh##S##0, fx[rt][0], aA, 0, 0, 0); \
        aA = __builtin_amdgcn_mfma_f32_16x16x32_bf16(wl##S##0, fx[rt][0], aA, 0, 0, 0); \
        aB = __builtin_amdgcn_mfma_f32_16x16x32_bf16(wh##S##1, fx[rt][1], aB, 0, 0, 0); \
        aB = __builtin_amdgcn_mfma_f32_16x16x32_bf16(wl##S##1, fx[rt][1], aB, 0, 0, 0); \
        _Pragma("unroll")                                                     \
        for (int r = 0; r < 4; ++r) {                                        \
          const float val = fmaf(-2.f, aA[r] + aB[r], w2p[r]);                \
          const unsigned u = (flipf(val) & 0xFFFFFC00u) |                     \
                             (unsigned)((c) * 16 + grp * 4 + r);              \
          const unsigned mx = m1[rt] > u ? m1[rt] : u;                        \
          m1[rt] = m1[rt] < u ? m1[rt] : u;                                   \
          m2[rt] = m2[rt] < mx ? m2[rt] : mx;                                 \
        } } }

__global__ __launch_bounds__(512, 4) void score_kernel(
        const float* __restrict__ z,
        const unsigned short* __restrict__ wh, const unsigned short* __restrict__ wl,
        const float* __restrict__ w2, unsigned* __restrict__ kscr) {
    __shared__ __attribute__((aligned(16))) unsigned short sxt[64][260];
    __shared__ float w2s[KCODES];

    const int tid = threadIdx.x;
    const int lane = tid & 63, wid = tid >> 6;
    const int col = lane & 15, grp = lane >> 4;
    const int nb = blockIdx.x * 256;
    const int b = nb >> 12, hb = (nb >> 6) & 63;

    for (int i = tid; i < KCODES; i += 512) w2s[i] = w2[i];
    {
        const int h = lane >> 4, w4 = (lane & 15) * 4;
        const int row = h * 64 + w4;
#pragma unroll
        for (int it = 0; it < 8; ++it) {
            const int d = wid + 8 * it;
            const float4 v = *(const float4*)&z[((size_t)(b * 64 + d)) * HW + (hb + h) * 64 + w4];
            ushort4 u;
            u.x = (unsigned short)bf16rne(v.x);
            u.y = (unsigned short)bf16rne(v.y);
            u.z = (unsigned short)bf16rne(v.z);
            u.w = (unsigned short)bf16rne(v.w);
            *(ushort4*)&sxt[d][row] = u;
        }
    }
    __syncthreads();

    bf16x8 fx[2][2];
#pragma unroll
    for (int rt = 0; rt < 2; ++rt)
#pragma unroll
        for (int kh = 0; kh < 2; ++kh) {
            const int row = wid * 32 + rt * 16 + col;
            bf16x8 f;
#pragma unroll
            for (int j = 0; j < 8; ++j)
                f[j] = (short)sxt[kh * 32 + grp * 8 + j][row];
            fx[rt][kh] = f;
        }

    unsigned m1[2] = {~0u, ~0u}, m2[2] = {~0u, ~0u};
    bf16x8 whA0, whA1, wlA0, wlA1, whB0, whB1, wlB0, wlB1;

    CBLOAD(A, 0)
    for (int c = 0; c < 64; c += 2) {
        CBLOAD(B, c + 1)
        CBCOMP(A, c)
        if (c + 2 < 64) CBLOAD(A, c + 2)
        CBCOMP(B, c + 1)
    }
#pragma unroll
    for (int rt = 0; rt < 2; ++rt) {
        for (int off = 16; off <= 32; off <<= 1) {
            const unsigned o1 = (unsigned)__shfl_xor((int)m1[rt], off, 64);
            const unsigned o2 = (unsigned)__shfl_xor((int)m2[rt], off, 64);
            const unsigned mx = m1[rt] > o1 ? m1[rt] : o1;
            m1[rt] = m1[rt] < o1 ? m1[rt] : o1;
            const unsigned t2 = m2[rt] < o2 ? m2[rt] : o2;
            m2[rt] = t2 < mx ? t2 : mx;
        }
        if (grp == 0) {
            const bool fl = (unflip_val(m2[rt]) - unflip_val(m1[rt])) < GAPTHR;
            kscr[nb + wid * 32 + rt * 16 + col] =
                (m1[rt] & 1023u) | (fl ? 0x80000000u : 0u);
        }
    }
}

__global__ __launch_bounds__(512, 4) void output_kernel(
        const float* __restrict__ z, const float* __restrict__ emb,
        const float* __restrict__ embT, const float* __restrict__ w2,
        float* __restrict__ out, const unsigned* __restrict__ kscr,
        float* __restrict__ esum_p, unsigned* __restrict__ cnt_p,
        float* __restrict__ lossb, int pmask) {
    __shared__ __attribute__((aligned(16))) unsigned short sxt[64][260];
    __shared__ unsigned k1s[256];
    __shared__ float redl[8];

    const int tid = threadIdx.x;
    const int lane = tid & 63, wid = tid >> 6;
    const int nb = blockIdx.x * 256;
    const int b = nb >> 12, hb = (nb >> 6) & 63;

    {
        const int h = lane >> 4, w4 = (lane & 15) * 4;
        const int row = h * 64 + w4;
#pragma unroll
        for (int it = 0; it < 8; ++it) {
            const int d = wid + 8 * it;
            const float4 v = *(const float4*)&z[((size_t)(b * 64 + d)) * HW + (hb + h) * 64 + w4];
            ushort4 u;
            u.x = (unsigned short)bf16rne(v.x);
            u.y = (unsigned short)bf16rne(v.y);
            u.z = (unsigned short)bf16rne(v.z);
            u.w = (unsigned short)bf16rne(v.w);
            *(ushort4*)&sxt[d][row] = u;
        }
    }

    unsigned kf = 0;
    if (lane < 32) kf = kscr[nb + wid * 32 + lane];
    int k1 = (int)(kf & 1023u);
    unsigned long long need = __ballot((lane < 32) && (kf & 0x80000000u));
    while (need) {
        const int src = __ffsll(need) - 1;
        need &= need - 1;
        const int nr = nb + wid * 32 + src;
        const int wq = nr & 63, hq = (nr >> 6) & 63, bq = nr >> 12;
        const float xv = z[(size_t)bq * DDIM * HW + (size_t)lane * HW + hq * 64 + wq];
        const float p = mul_rn(xv, xv);
        float r = 0.f;
        for (int i = 0; i < 8; ++i) {
            const float t = __shfl(p, (i << 3) + (lane & 7), 64);
            r = add_rn(r, t);
        }
        const float s01 = add_rn(r, __shfl_xor(r, 1, 64));
        const float s03 = add_rn(s01, __shfl_xor(s01, 2, 64));
        const float s07 = add_rn(s03, __shfl_xor(s03, 4, 64));
        const float x2s = __shfl(s07, 0, 64);

        float acc[16];
#pragma unroll
        for (int j = 0; j < 16; ++j) acc[j] = 0.f;
        for (int d = 0; d < DDIM; ++d) {
            const float xd = __shfl(xv, d, 64);
            const float* ecol = embT + (size_t)d * KCODES + lane;
#pragma unroll
            for (int j = 0; j < 16; ++j)
                acc[j] = fmaf(ecol[64 * j], xd, acc[j]);
        }
        float bv = 1e30f;
        int bk = KCODES;
#pragma unroll
        for (int j = 0; j < 16; ++j) {
            const int kk = lane + 64 * j;
            const float s  = add_rn(x2s, w2[kk]);
            const float dv = sub2_rn(s, acc[j]);
            if (dv < bv) { bv = dv; bk = kk; }
        }
        for (int off = 32; off > 0; off >>= 1) {
            const float ov = __shfl_xor(bv, off, 64);
            const int   ok = __shfl_xor(bk, off, 64);
            if (ov < bv || (ov == bv && ok < bk)) { bv = ov; bk = ok; }
        }
        if (lane == src) k1 = bk;
    }
    if (lane < 32) k1s[wid * 32 + lane] = (unsigned)k1;
    __syncthreads();

    const int part = blockIdx.x & pmask;
    if (tid < 256) {
        const unsigned myk = k1s[tid];
        out[OFF_IDX + (size_t)(nb + tid)] = (float)myk;
        atomicAdd(&cnt_p[part * KCODES + myk], 1u);
    }

    float ls = 0.f;
    {
        const int h = lane >> 4, w4 = (lane & 15) * 4;
        const int row = h * 64 + w4;
#pragma unroll 2
        for (int it = 0; it < 8; ++it) {
            const int d = wid + 8 * it;
            float4 q;
            float* qp = (float*)&q;
#pragma unroll
            for (int j = 0; j < 4; ++j) {
                const unsigned k = k1s[row + j];
                const float wv = emb[(size_t)k * DDIM + d];
                qp[j] = wv;
                const float diff = bfu2f(sxt[d][row + j]) - wv;
                ls = fmaf(diff, diff, ls);
            }
            *(float4*)&out[((size_t)(b * 64 + d)) * HW + (hb + h) * 64 + w4] = q;
        }
    }
#pragma unroll
    for (int off = 32; off > 0; off >>= 1) ls += __shfl_down(ls, off, 64);
    if (lane == 0) redl[wid] = ls;
    __syncthreads();
    if (tid == 0) {
        float t = 0.f;
#pragma unroll
        for (int i = 0; i < 8; ++i) t += redl[i];
        lossb[blockIdx.x] = t;
    }
    {
        float* ep = esum_p + (size_t)part * 65536;
        for (int r = 0; r < 32; ++r) {
            const int row = wid * 32 + r;
            atomicAdd(&ep[(size_t)k1s[row] * DDIM + lane], bfu2f(sxt[lane][row]));
        }
    }
}

__global__ __launch_bounds__(1024) void finalize1_kernel(
        const float* __restrict__ cs, float* __restrict__ out,
        const unsigned* __restrict__ cnt_p, const float* __restrict__ lossb,
        float* __restrict__ smoothed, int P) {
    const int k = threadIdx.x;
    unsigned c = 0;
    for (int p = 0; p < P; ++p) c += cnt_p[p * KCODES + k];
    const float ncs = fmaf(0.01f, (float)c, 0.99f * cs[k]);

    __shared__ float red[1024];
    red[k] = ncs;
    __syncthreads();
    for (int s = 512; s > 0; s >>= 1) {
        if (k < s) red[k] += red[k + s];
        __syncthreads();
    }
    const float nn = red[0];
    smoothed[k] = (ncs + 1e-5f) / (nn + 1024.f * 1e-5f) * nn;
    out[OFF_NCS + (size_t)k] = ncs;

    __syncthreads();
    red[k] = (k < 512) ? lossb[k] : 0.f;
    __syncthreads();
    for (int s = 512; s > 0; s >>= 1) {
        if (k < s) red[k] += red[k + s];
        __syncthreads();
    }
    if (k == 0) out[OFF_LOSS] = 0.25f * red[0] / 8388608.f;
}

__global__ __launch_bounds__(256) void finalize2_kernel(
        const float* __restrict__ eavg, float* __restrict__ out,
        const float* __restrict__ esum_p, const float* __restrict__ smoothed,
        int P) {
    const int e = blockIdx.x * 256 + threadIdx.x;
    float s = 0.f;
    for (int p = 0; p < P; ++p) s += esum_p[(size_t)p * 65536 + e];
    const float ea = fmaf(0.01f, s, 0.99f * eavg[e]);
    out[OFF_EAVG + (size_t)e] = ea;
    out[OFF_EMB  + (size_t)e] = ea / smoothed[e >> 6];
}

// =========================================================================

extern "C" void kernel_launch(void* const* d_in, const int* in_sizes, int n_in,
                              void* d_out, int out_size, void* d_ws, size_t ws_size,
                              hipStream_t stream) {
    const float* z    = (const float*)d_in[0];
    const float* emb  = (const float*)d_in[1];
    const float* cs   = (const float*)d_in[2];
    const float* eavg = (const float*)d_in[3];
    float* out = (float*)d_out;

    unsigned short* wh = (unsigned short*)((char*)d_out + SCR_B0);
    unsigned short* wl = (unsigned short*)((char*)d_out + SCR_WLO);
    float*          w2 = (float*)((char*)d_out + SCR_W2O);
    char* ws = (char*)d_ws;

    if (ws_size >= FWS_TOTAL) {
        unsigned short*     xT   = (unsigned short*)ws;
        float*              scs  = (float*)(ws + FWS_SCS);
        unsigned*           list = (unsigned*)(ws + FWS_LIST);
        unsigned long long* rmin = (unsigned long long*)(ws + FWS_RMIN);
        unsigned*           cntr = (unsigned*)(ws + FWS_CNTR);
        float*              lossA = (float*)(ws + FWS_LOSSA);
        float*              embT = (float*)(ws + FWS_KSCR); // prep scratch; dead after

        (void)hipMemsetAsync(ws + FWS_CNTR, 0, 8, stream);
        prep_kernel<<<16, 256, 0, stream>>>(emb, cs, wh, wl, w2, embT, scs);
        score2_kernel<<<NROWS / 256, 512, 0, stream>>>(
            z, emb, wh, wl, w2, out, xT, list, rmin, cntr);
        rescanb_kernel<<<256, 256, 0, stream>>>(z, emb, w2, list, cntr, rmin);
        fix_kernel<<<LCAP / 4, 256, 0, stream>>>(list, rmin, cntr, emb, out);
        gatherfin_kernel<<<KCODES, 256, 0, stream>>>(
            out + OFF_IDX, xT, emb, cs, eavg, w2, scs, out, lossA);
        lossfin_kernel<<<1, 64, 0, stream>>>(lossA, out);
    } else {
        int P = 1;
        for (int p = 16; p >= 1; p >>= 1)
            if (ws_size >= WSO_ESUM + (size_t)p * 262144ull) { P = p; break; }

        float*    embT   = (float*)ws;
        unsigned* kscr   = (unsigned*)(ws + WSO_KSCR);
        float*    lossb  = (float*)(ws + WSO_LOSSB);
        float*    smooth = (float*)(ws + WSO_SMOOTH);
        unsigned* cnt_p  = (unsigned*)(ws + WSO_CNT);
        float*    esum_p = (float*)(ws + WSO_ESUM);

        (void)hipMemsetAsync(ws + WSO_CNT, 0, 65536 + (size_t)P * 262144ull, stream);
        prep_kernel<<<16, 256, 0, stream>>>(emb, cs, wh, wl, w2, embT,
                                            (float*)(ws + WSO_SMOOTH));
        score_kernel<<<NROWS / 256, 512, 0, stream>>>(z, wh, wl, w2, kscr);
        output_kernel<<<NROWS / 256, 512, 0, stream>>>(
            z, emb, embT, w2, out, kscr, esum_p, cnt_p, lossb, P - 1);
        finalize1_kernel<<<1, 1024, 0, stream>>>(cs, out, cnt_p, lossb, smooth, P);
        finalize2_kernel<<<256, 256, 0, stream>>>(eavg, out, esum_p, smooth, P);
    }
}

// Round 22
// 262.005 us; speedup vs baseline: 1.0732x; 1.0732x over previous
//
#include <hip/hip_runtime.h>
#include <hip/hip_bf16.h>

#define NROWS 131072
#define DDIM  64
#define KCODES 1024
#define HW    4096

// d_out is FLOAT32. Element offsets (reference return order):
#define OFF_ZQ   0ull
#define OFF_IDX  8388608ull
#define OFF_LOSS 8519680ull
#define OFF_EMB  8519681ull
#define OFF_NCS  8585217ull
#define OFF_EAVG 8586241ull

// d_out tail scratch (overlays emb/ncs outputs; consumed then rewritten):
#define SCR_B0    34078724ull
#define SCR_WLO   (SCR_B0 + 131072ull)
#define SCR_W2O   (SCR_B0 + 262144ull)
#define LCAP      20480u

// ---- fast-path ws layout ----
//   xT bf16[131072][64] @ 0 | kidx u16[131072] @ FWS_KSCR (262144 B)
#define FWS_KSCR   16777216ull
#define FWS_SCS    17047556ull
#define FWS_LIST   17301504ull
#define FWS_RMIN   17383424ull
#define FWS_CNTR   17547264ull
#define FWS_LOSSA  17547268ull
#define FWS_TOTAL  17547272ull

// ---- fallback (round-11 verbatim) ws layout ----
#define WSO_KSCR   262144ull
#define WSO_LOSSB  786432ull
#define WSO_SMOOTH 788480ull
#define WSO_CNT    792576ull
#define WSO_ESUM   858112ull

#define GAPTHR 8e-5f

typedef __attribute__((ext_vector_type(8))) short bf16x8;
typedef __attribute__((ext_vector_type(4))) float f32x4;

#define GLOAD_LDS16(gp, lp)                                                     \
    __builtin_amdgcn_global_load_lds(                                           \
        (const __attribute__((address_space(1))) void*)(gp),                    \
        (__attribute__((address_space(3))) void*)(lp), 16, 0, 0)

__device__ __forceinline__ float np_sumsq64(const float* v) {
#pragma clang fp contract(off)
    float r0 = v[0]*v[0], r1 = v[1]*v[1], r2 = v[2]*v[2], r3 = v[3]*v[3];
    float r4 = v[4]*v[4], r5 = v[5]*v[5], r6 = v[6]*v[6], r7 = v[7]*v[7];
    for (int i = 8; i < 64; i += 8) {
        r0 += v[i+0]*v[i+0]; r1 += v[i+1]*v[i+1];
        r2 += v[i+2]*v[i+2]; r3 += v[i+3]*v[i+3];
        r4 += v[i+4]*v[i+4]; r5 += v[i+5]*v[i+5];
        r6 += v[i+6]*v[i+6]; r7 += v[i+7]*v[i+7];
    }
    return ((r0+r1)+(r2+r3))+((r4+r5)+(r6+r7));
}
__device__ __forceinline__ float mul_rn(float a, float b) {
#pragma clang fp contract(off)
    return a * b;
}
__device__ __forceinline__ float add_rn(float a, float b) {
#pragma clang fp contract(off)
    return a + b;
}
__device__ __forceinline__ float sub2_rn(float s, float a) {
#pragma clang fp contract(off)
    return s - 2.0f * a;
}
__device__ __forceinline__ unsigned bf16rne(float v) {
    unsigned b = __float_as_uint(v);
    return (b + 0x7FFFu + ((b >> 16) & 1u)) >> 16;
}
__device__ __forceinline__ float bfu2f(unsigned short u) {
    return __uint_as_float(((unsigned)u) << 16);
}
__device__ __forceinline__ unsigned flipf(float v) {
    unsigned b = __float_as_uint(v);
    return b ^ (0x80000000u | (unsigned)((int)b >> 31));
}
__device__ __forceinline__ float unflip_val(unsigned u) {
    u &= 0xFFFFFC00u;
    unsigned mask = 0x80000000u | (unsigned)((int)(~u) >> 31);
    return __uint_as_float(u ^ mask);
}

__global__ __launch_bounds__(256) void prep_kernel(
        const float* __restrict__ emb, const float* __restrict__ cs,
        unsigned short* __restrict__ wh, unsigned short* __restrict__ wl,
        float* __restrict__ w2, float* __restrict__ embT,
        float* __restrict__ scs) {
    __shared__ float tile[64][65];
    __shared__ float sred[4];
    const int t = threadIdx.x;
    const int kb = blockIdx.x * 64;
#pragma unroll
    for (int i = 0; i < 16; ++i) {
        const int e = t + i * 256;
        const int kl = e >> 6, d = e & 63;
        const float v = emb[(size_t)(kb + kl) * DDIM + d];
        tile[kl][d] = v;
        const unsigned rh = bf16rne(v);
        const float lv = v - bfu2f((unsigned short)rh);
        wh[(size_t)(kb + kl) * DDIM + d] = (unsigned short)rh;
        wl[(size_t)(kb + kl) * DDIM + d] = (unsigned short)bf16rne(lv);
    }
    __syncthreads();
    if (t < 64) w2[kb + t] = np_sumsq64(&tile[t][0]);
    if (embT) {   // fallback path only; fast path never reads embT
#pragma unroll
        for (int i = 0; i < 16; ++i) {
            const int e = t + i * 256;
            const int d = e >> 6, kl = e & 63;
            embT[(size_t)d * KCODES + kb + kl] = tile[kl][d];
        }
    }
    if (blockIdx.x == 0) {
        float v = cs[t * 4] + cs[t * 4 + 1] + cs[t * 4 + 2] + cs[t * 4 + 3];
#pragma unroll
        for (int off = 32; off > 0; off >>= 1) v += __shfl_down(v, off, 64);
        if ((t & 63) == 0) sred[t >> 6] = v;
        __syncthreads();
        if (t == 0) scs[0] = sred[0] + sred[1] + sred[2] + sred[3];
    }
}

#define CBLOAD(S, c)                                                          \
    { const size_t a_ = ((size_t)(((c) * 16 + col) * DDIM + grp * 8));        \
      wh##S##0 = *(const bf16x8*)(wh + a_);                                   \
      wh##S##1 = *(const bf16x8*)(wh + a_ + 32);                              \
      wl##S##0 = *(const bf16x8*)(wl + a_);                                   \
      wl##S##1 = *(const bf16x8*)(wl + a_ + 32); }

// score2 (r20-proven 512-row tile): MFMA top-2 + xT dump + idx/kidx + z_q
// + flagged-list append; LDS codebook double-buffer + w2 in LDS.
__global__ __launch_bounds__(512, 2) void score2_kernel(
        const float* __restrict__ z, const float* __restrict__ emb,
        const unsigned short* __restrict__ wh, const unsigned short* __restrict__ wl,
        const float* __restrict__ w2g, float* __restrict__ out,
        unsigned short* __restrict__ xT, unsigned short* __restrict__ kidx,
        unsigned* __restrict__ list,
        unsigned long long* __restrict__ rmin, unsigned* __restrict__ counter) {
    __shared__ __attribute__((aligned(16))) unsigned short sxt[64][512];
    __shared__ __attribute__((aligned(16))) unsigned short cb[2][2][4][512];
    __shared__ float w2s[KCODES];
    __shared__ unsigned k1s[512];

    const int tid = threadIdx.x;
    const int lane = tid & 63, wid = tid >> 6;
    const int col = lane & 15, grp = lane >> 4;
    const int nb = blockIdx.x * 512;
    const int b = nb >> 12, hb = (nb >> 6) & 63;
    const int w4 = (tid & 15) * 4, h8 = (tid >> 4) & 7, dg = tid >> 7;

    for (int i = tid; i < KCODES; i += 512) w2s[i] = w2g[i];

    // stage 512 rows of x into LDS (transposed, bf16-hi)
    {
#pragma unroll
        for (int j = 0; j < 16; ++j) {
            const int d = dg * 16 + j;
            const float4 v = *(const float4*)&z[((size_t)(b * 64 + d)) * HW + (hb + h8) * 64 + w4];
            ushort4 u;
            u.x = (unsigned short)bf16rne(v.x);
            u.y = (unsigned short)bf16rne(v.y);
            u.z = (unsigned short)bf16rne(v.z);
            u.w = (unsigned short)bf16rne(v.w);
            *(ushort4*)&sxt[d][h8 * 64 + w4] = u;
        }
    }
    __syncthreads();

    // fragments (wave owns 64 rows) + xT dump straight from fragments
    bf16x8 fx[4][2];
#pragma unroll
    for (int rt = 0; rt < 4; ++rt)
#pragma unroll
        for (int kh = 0; kh < 2; ++kh) {
            const int row = wid * 64 + rt * 16 + col;
            bf16x8 f;
#pragma unroll
            for (int j = 0; j < 8; ++j)
                f[j] = (short)sxt[kh * 32 + grp * 8 + j][row];
            fx[rt][kh] = f;
            *(bf16x8*)&xT[(size_t)(nb + row) * DDIM + kh * 32 + grp * 8] = f;
        }

    // codebook staging (r9-proven geometry): 1KB per wave per round
    const int pr = wid >> 2, sW = (wid >> 1) & 1, khW = wid & 1;
    const unsigned short* gsrc = (pr ? wl : wh) + khW * 32 + grp * 8
                               + (size_t)(sW * 16 + col) * DDIM;

    GLOAD_LDS16(gsrc, &cb[0][pr][sW * 2 + khW][0]);
    asm volatile("s_waitcnt vmcnt(0)" ::: "memory");
    __builtin_amdgcn_s_barrier();

    unsigned m1[4] = {~0u, ~0u, ~0u, ~0u}, m2[4] = {~0u, ~0u, ~0u, ~0u};

    for (int rd = 0; rd < 32; ++rd) {
        const int cur = rd & 1;
        if (rd < 31)
            GLOAD_LDS16(gsrc + (size_t)(rd + 1) * 32 * DDIM,
                        &cb[cur ^ 1][pr][sW * 2 + khW][0]);
#pragma unroll
        for (int s = 0; s < 2; ++s) {
            const bf16x8 vh0 = *(const bf16x8*)&cb[cur][0][s * 2 + 0][lane * 8];
            const bf16x8 vh1 = *(const bf16x8*)&cb[cur][0][s * 2 + 1][lane * 8];
            const bf16x8 vl0 = *(const bf16x8*)&cb[cur][1][s * 2 + 0][lane * 8];
            const bf16x8 vl1 = *(const bf16x8*)&cb[cur][1][s * 2 + 1][lane * 8];
            const int c = rd * 2 + s;
            const float4 w2v = *(const float4*)&w2s[c * 16 + grp * 4];
            const float* w2p = (const float*)&w2v;
#pragma unroll
            for (int rt = 0; rt < 4; ++rt) {
                f32x4 a = {0.f, 0.f, 0.f, 0.f};
                a = __builtin_amdgcn_mfma_f32_16x16x32_bf16(vh0, fx[rt][0], a, 0, 0, 0);
                a = __builtin_amdgcn_mfma_f32_16x16x32_bf16(vl0, fx[rt][0], a, 0, 0, 0);
                a = __builtin_amdgcn_mfma_f32_16x16x32_bf16(vh1, fx[rt][1], a, 0, 0, 0);
                a = __builtin_amdgcn_mfma_f32_16x16x32_bf16(vl1, fx[rt][1], a, 0, 0, 0);
#pragma unroll
                for (int r = 0; r < 4; ++r) {
                    const float val = fmaf(-2.f, a[r], w2p[r]);
                    const unsigned u = (flipf(val) & 0xFFFFFC00u) |
                                       (unsigned)(c * 16 + grp * 4 + r);
                    const unsigned mx = m1[rt] > u ? m1[rt] : u;
                    m1[rt] = m1[rt] < u ? m1[rt] : u;
                    m2[rt] = m2[rt] < mx ? m2[rt] : mx;
                }
            }
        }
        asm volatile("s_waitcnt vmcnt(0) lgkmcnt(0)" ::: "memory");
        __builtin_amdgcn_s_barrier();
    }

    // merge top-2 across the 4 grp-lanes sharing each row
#pragma unroll
    for (int rt = 0; rt < 4; ++rt) {
        for (int off = 16; off <= 32; off <<= 1) {
            const unsigned o1 = (unsigned)__shfl_xor((int)m1[rt], off, 64);
            const unsigned o2 = (unsigned)__shfl_xor((int)m2[rt], off, 64);
            const unsigned mx = m1[rt] > o1 ? m1[rt] : o1;
            m1[rt] = m1[rt] < o1 ? m1[rt] : o1;
            const unsigned t2 = m2[rt] < o2 ? m2[rt] : o2;
            m2[rt] = t2 < mx ? t2 : mx;
        }
    }

    bool flag[4];
    unsigned long long mrt[4];
    unsigned wavecnt = 0;
#pragma unroll
    for (int rt = 0; rt < 4; ++rt) {
        flag[rt] = (grp == 0) &&
                   ((unflip_val(m2[rt]) - unflip_val(m1[rt])) < GAPTHR);
        mrt[rt] = __ballot(flag[rt]);
        wavecnt += (unsigned)__popcll(mrt[rt]);
    }

    // provisional idx + kidx + k1s (fix_kernel rewrites flagged entries later)
    if (grp == 0) {
#pragma unroll
        for (int rt = 0; rt < 4; ++rt) {
            const unsigned k = m1[rt] & 1023u;
            const int n = nb + wid * 64 + rt * 16 + col;
            out[OFF_IDX + (size_t)n] = (float)k;
            kidx[n] = (unsigned short)k;
            k1s[wid * 64 + rt * 16 + col] = k;
        }
    }

    // dense list append: one atomic per wave
    unsigned base = 0;
    if (lane == 0 && wavecnt) base = atomicAdd(counter, wavecnt);
    base = (unsigned)__shfl((int)base, 0, 64);
    unsigned offrt = 0;
#pragma unroll
    for (int rt = 0; rt < 4; ++rt) {
        if (flag[rt]) {
            const unsigned offin =
                (unsigned)__popcll(mrt[rt] & ((lane == 0) ? 0ull : (~0ull >> (64 - lane))));
            const unsigned slot = base + offrt + offin;
            if (slot < LCAP) {
                list[slot] = (unsigned)(nb + wid * 64 + rt * 16 + col);
                rmin[slot] = ~0ull;
            }
        }
        offrt += (unsigned)__popcll(mrt[rt]);
    }

    // fused z_q write (provisional; fix rewrites flagged rows)
    __syncthreads();
    {
        const int r0 = h8 * 64 + w4;
        const float* e0 = emb + (size_t)k1s[r0 + 0] * DDIM;
        const float* e1 = emb + (size_t)k1s[r0 + 1] * DDIM;
        const float* e2 = emb + (size_t)k1s[r0 + 2] * DDIM;
        const float* e3 = emb + (size_t)k1s[r0 + 3] * DDIM;
#pragma unroll
        for (int j = 0; j < 16; ++j) {
            const int d = dg * 16 + j;
            float4 q;
            q.x = e0[d]; q.y = e1[d]; q.z = e2[d]; q.w = e3[d];
            *(float4*)&out[((size_t)(b * 64 + d)) * HW + (hb + h8) * 64 + w4] = q;
        }
    }
}

// rescan_b: batched np-exact rescan. lane = flagged row; K split 8 ways.
__global__ __launch_bounds__(256, 1) void rescanb_kernel(
        const float* __restrict__ z, const float* __restrict__ emb,
        const float* __restrict__ w2, const unsigned* __restrict__ list,
        const unsigned* __restrict__ counter,
        unsigned long long* __restrict__ rmin) {
    const int lane = threadIdx.x & 63;
    const int wid = __builtin_amdgcn_readfirstlane(threadIdx.x >> 6);
    unsigned cnt = __builtin_amdgcn_readfirstlane(*counter);
    if (cnt > LCAP) cnt = LCAP;
    if (cnt == 0) return;
    const unsigned W = ((cnt + 63) >> 6) * 8;

    for (unsigned w = blockIdx.x * 4 + wid; w < W; w += gridDim.x * 4) {
        const unsigned g = w >> 3, p = w & 7;
        const unsigned slot = g * 64 + lane;
        const bool valid = slot < cnt;
        const unsigned n = list[valid ? slot : 0];
        const unsigned hw = n & 4095u, bb = n >> 12;

        float x[64];
#pragma unroll
        for (int d = 0; d < 64; ++d)
            x[d] = z[(size_t)(bb * 64 + d) * (size_t)HW + hw];

        float r[8];
#pragma unroll
        for (int j = 0; j < 8; ++j) r[j] = mul_rn(x[j], x[j]);
#pragma unroll
        for (int i = 8; i < 64; i += 8)
#pragma unroll
            for (int j = 0; j < 8; ++j)
                r[j] = add_rn(r[j], mul_rn(x[i + j], x[i + j]));
        const float x2 = add_rn(add_rn(add_rn(r[0], r[1]), add_rn(r[2], r[3])),
                                add_rn(add_rn(r[4], r[5]), add_rn(r[6], r[7])));

        unsigned long long best = ~0ull;
        const int k0 = (int)p * 128;
        for (int k = k0; k < k0 + 128; k += 2) {
            const float* wa = emb + (size_t)k * DDIM;
            const float* wb = wa + DDIM;
            float aa = 0.f, ab = 0.f;
#pragma unroll
            for (int d = 0; d < 64; ++d) {
                aa = fmaf(x[d], wa[d], aa);   // np seq-fma, d ascending
                ab = fmaf(x[d], wb[d], ab);
            }
            const float da = sub2_rn(add_rn(x2, w2[k]),     aa);
            const float db = sub2_rn(add_rn(x2, w2[k + 1]), ab);
            const unsigned long long ua =
                ((unsigned long long)flipf(da) << 10) | (unsigned long long)k;
            const unsigned long long ub =
                ((unsigned long long)flipf(db) << 10) | (unsigned long long)(k + 1);
            best = best < ua ? best : ua;
            best = best < ub ? best : ub;
        }
        if (valid) atomicMin(&rmin[slot], best);
    }
}

// fix: rewrite idx, kidx AND z_q for flagged rows (lane = d)
__global__ __launch_bounds__(256) void fix_kernel(
        const unsigned* __restrict__ list, const unsigned long long* __restrict__ rmin,
        const unsigned* __restrict__ counter, const float* __restrict__ emb,
        unsigned short* __restrict__ kidx, float* __restrict__ out) {
    unsigned cnt = *counter;
    if (cnt > LCAP) cnt = LCAP;
    const int lane = threadIdx.x & 63, ws = threadIdx.x >> 6;
    const unsigned t = blockIdx.x * 4 + ws;
    if (t >= cnt) return;
    const unsigned long long u = rmin[t];
    if (u == ~0ull) return;
    const unsigned k = (unsigned)(u & 1023ull);
    const unsigned n = list[t];
    if (lane == 0) {
        out[OFF_IDX + (size_t)n] = (float)k;
        kidx[n] = (unsigned short)k;
    }
    const unsigned hw = n & 4095u, bb = n >> 12;
    out[((size_t)(bb * 64 + lane)) * HW + hw] = emb[(size_t)k * DDIM + lane];
}

// gatherfin: 1 block/code; scan kidx (u16) + gather xT; finalize outputs
__global__ __launch_bounds__(256) void gatherfin_kernel(
        const unsigned short* __restrict__ kidx, const unsigned short* __restrict__ xT,
        const float* __restrict__ emb, const float* __restrict__ cs,
        const float* __restrict__ eavg, const float* __restrict__ w2,
        const float* __restrict__ scs, float* __restrict__ out,
        float* __restrict__ lossA) {
    const int k = blockIdx.x;
    const int lane = threadIdx.x & 63, wid = threadIdx.x >> 6;
    const unsigned uk = (unsigned)k;
    float acc = 0.f, s2 = 0.f;
    unsigned cnt = 0;
    const int wbase = wid * 32768;

    uint4 cur = *(const uint4*)&kidx[wbase + lane * 8];
    for (int it = 0; it < 64; ++it) {
        uint4 nxt;
        if (it + 1 < 64)
            nxt = *(const uint4*)&kidx[wbase + (it + 1) * 512 + lane * 8];
        const unsigned* cp = (const unsigned*)&cur;
#pragma unroll
        for (int j = 0; j < 4; ++j) {
            const unsigned v = cp[j];
#pragma unroll
            for (int h = 0; h < 2; ++h) {
                const unsigned code = h ? (v >> 16) : (v & 0xFFFFu);
                unsigned long long m = __ballot(code == uk);
                cnt += (unsigned)__popcll(m);
                while (m) {
                    const int src = __ffsll(m) - 1;
                    m &= m - 1;
                    const int n = wbase + it * 512 + src * 8 + j * 2 + h;
                    const float xv = bfu2f(xT[(size_t)n * DDIM + lane]);
                    acc += xv;
                    s2 = fmaf(xv, xv, s2);
                }
            }
        }
        cur = nxt;
    }
#pragma unroll
    for (int off = 32; off > 0; off >>= 1) s2 += __shfl_down(s2, off, 64);
    __shared__ float sacc[4][64];
    __shared__ float ssx2[4];
    __shared__ unsigned scnt[4];
    sacc[wid][lane] = acc;
    if (lane == 0) { ssx2[wid] = s2; scnt[wid] = cnt; }
    __syncthreads();
    if (wid == 0) {
        const float es = sacc[0][lane] + sacc[1][lane] + sacc[2][lane] + sacc[3][lane];
        const float cntk = (float)(scnt[0] + scnt[1] + scnt[2] + scnt[3]);
        const float sx2 = ssx2[0] + ssx2[1] + ssx2[2] + ssx2[3];
        const float w2k = w2[k];                     // read BEFORE ncs write below
        const float wkd = emb[(size_t)k * DDIM + lane];

        float dt = es * wkd;
#pragma unroll
        for (int off = 32; off > 0; off >>= 1) dt += __shfl_down(dt, off, 64);

        const float ncs = fmaf(0.01f, cntk, 0.99f * cs[k]);
        const float nn  = fmaf(0.99f, scs[0], 1310.72f);   // 0.01 * 131072
        const float smoothed = (ncs + 1e-5f) / (nn + 1024.f * 1e-5f) * nn;

        if (lane == 0) {
            out[OFF_NCS + (size_t)k] = ncs;                 // overlays w2[k]
            atomicAdd(lossA, sx2 - 2.f * dt + cntk * w2k);
        }
        const float ea = fmaf(0.01f, es, 0.99f * eavg[(size_t)k * DDIM + lane]);
        out[OFF_EAVG + (size_t)k * DDIM + lane] = ea;
        out[OFF_EMB  + (size_t)k * DDIM + lane] = ea / smoothed;
    }
}

__global__ __launch_bounds__(64) void lossfin_kernel(
        const float* __restrict__ lossA, float* __restrict__ out) {
    if (threadIdx.x == 0)
        out[OFF_LOSS] = 0.25f * lossA[0] / 8388608.f;
}

// ====================== FALLBACK (round-11 verbatim) ======================

#define CBCOMP(S, c)                                                          \
    { const float4 w2v = *(const float4*)&w2s[(c) * 16 + grp * 4];            \
      const float* w2p = (const float*)&w2v;                                  \
      _Pragma("unroll")                                                       \
      for (int rt = 0; rt < 2; ++rt) {                                        \
        f32x4 aA = {0.f,0.f,0.f,0.f}, aB = {0.f,0.f,0.f,0.f};                 \
        aA = __builtin_amdgcn_mfma_f32_16x16x32_bf16(wh##S##0, fx[rt][0], aA, 0, 0, 0); \
        aA = __builtin_amdgcn_mfma_f32_16x16x32_bf16(wl##S##0, fx[rt][0], aA, 0, 0, 0); \
        aB = __builtin_amdgcn_mfma_f32_16x16x32_bf16(wh##S##1, fx[rt][1], aB, 0, 0, 0); \
        aB = __builtin_amdgcn_mfma_f32_16x16x32_bf16(wl##S##1, fx[rt][1], aB, 0, 0, 0); \
        _Pragma("unroll")                                                     \
        for (int r = 0; r < 4; ++r) {                                        \
          const float val = fmaf(-2.f, aA[r] + aB[r], w2p[r]);                \
          const unsigned u = (flipf(val) & 0xFFFFFC00u) |                     \
                             (unsigned)((c) * 16 + grp * 4 + r);              \
          const unsigned mx = m1[rt] > u ? m1[rt] : u;                        \
          m1[rt] = m1[rt] < u ? m1[rt] : u;                                   \
          m2[rt] = m2[rt] < mx ? m2[rt] : mx;                                 \
        } } }

__global__ __launch_bounds__(512, 4) void score_kernel(
        const float* __restrict__ z,
        const unsigned short* __restrict__ wh, const unsigned short* __restrict__ wl,
        const float* __restrict__ w2, unsigned* __restrict__ kscr) {
    __shared__ __attribute__((aligned(16))) unsigned short sxt[64][260];
    __shared__ float w2s[KCODES];

    const int tid = threadIdx.x;
    const int lane = tid & 63, wid = tid >> 6;
    const int col = lane & 15, grp = lane >> 4;
    const int nb = blockIdx.x * 256;
    const int b = nb >> 12, hb = (nb >> 6) & 63;

    for (int i = tid; i < KCODES; i += 512) w2s[i] = w2[i];
    {
        const int h = lane >> 4, w4 = (lane & 15) * 4;
        const int row = h * 64 + w4;
#pragma unroll
        for (int it = 0; it < 8; ++it) {
            const int d = wid + 8 * it;
            const float4 v = *(const float4*)&z[((size_t)(b * 64 + d)) * HW + (hb + h) * 64 + w4];
            ushort4 u;
            u.x = (unsigned short)bf16rne(v.x);
            u.y = (unsigned short)bf16rne(v.y);
            u.z = (unsigned short)bf16rne(v.z);
            u.w = (unsigned short)bf16rne(v.w);
            *(ushort4*)&sxt[d][row] = u;
        }
    }
    __syncthreads();

    bf16x8 fx[2][2];
#pragma unroll
    for (int rt = 0; rt < 2; ++rt)
#pragma unroll
        for (int kh = 0; kh < 2; ++kh) {
            const int row = wid * 32 + rt * 16 + col;
            bf16x8 f;
#pragma unroll
            for (int j = 0; j < 8; ++j)
                f[j] = (short)sxt[kh * 32 + grp * 8 + j][row];
            fx[rt][kh] = f;
        }

    unsigned m1[2] = {~0u, ~0u}, m2[2] = {~0u, ~0u};
    bf16x8 whA0, whA1, wlA0, wlA1, whB0, whB1, wlB0, wlB1;

    CBLOAD(A, 0)
    for (int c = 0; c < 64; c += 2) {
        CBLOAD(B, c + 1)
        CBCOMP(A, c)
        if (c + 2 < 64) CBLOAD(A, c + 2)
        CBCOMP(B, c + 1)
    }
#pragma unroll
    for (int rt = 0; rt < 2; ++rt) {
        for (int off = 16; off <= 32; off <<= 1) {
            const unsigned o1 = (unsigned)__shfl_xor((int)m1[rt], off, 64);
            const unsigned o2 = (unsigned)__shfl_xor((int)m2[rt], off, 64);
            const unsigned mx = m1[rt] > o1 ? m1[rt] : o1;
            m1[rt] = m1[rt] < o1 ? m1[rt] : o1;
            const unsigned t2 = m2[rt] < o2 ? m2[rt] : o2;
            m2[rt] = t2 < mx ? t2 : mx;
        }
        if (grp == 0) {
            const bool fl = (unflip_val(m2[rt]) - unflip_val(m1[rt])) < GAPTHR;
            kscr[nb + wid * 32 + rt * 16 + col] =
                (m1[rt] & 1023u) | (fl ? 0x80000000u : 0u);
        }
    }
}

__global__ __launch_bounds__(512, 4) void output_kernel(
        const float* __restrict__ z, const float* __restrict__ emb,
        const float* __restrict__ embT, const float* __restrict__ w2,
        float* __restrict__ out, const unsigned* __restrict__ kscr,
        float* __restrict__ esum_p, unsigned* __restrict__ cnt_p,
        float* __restrict__ lossb, int pmask) {
    __shared__ __attribute__((aligned(16))) unsigned short sxt[64][260];
    __shared__ unsigned k1s[256];
    __shared__ float redl[8];

    const int tid = threadIdx.x;
    const int lane = tid & 63, wid = tid >> 6;
    const int nb = blockIdx.x * 256;
    const int b = nb >> 12, hb = (nb >> 6) & 63;

    {
        const int h = lane >> 4, w4 = (lane & 15) * 4;
        const int row = h * 64 + w4;
#pragma unroll
        for (int it = 0; it < 8; ++it) {
            const int d = wid + 8 * it;
            const float4 v = *(const float4*)&z[((size_t)(b * 64 + d)) * HW + (hb + h) * 64 + w4];
            ushort4 u;
            u.x = (unsigned short)bf16rne(v.x);
            u.y = (unsigned short)bf16rne(v.y);
            u.z = (unsigned short)bf16rne(v.z);
            u.w = (unsigned short)bf16rne(v.w);
            *(ushort4*)&sxt[d][row] = u;
        }
    }

    unsigned kf = 0;
    if (lane < 32) kf = kscr[nb + wid * 32 + lane];
    int k1 = (int)(kf & 1023u);
    unsigned long long need = __ballot((lane < 32) && (kf & 0x80000000u));
    while (need) {
        const int src = __ffsll(need) - 1;
        need &= need - 1;
        const int nr = nb + wid * 32 + src;
        const int wq = nr & 63, hq = (nr >> 6) & 63, bq = nr >> 12;
        const float xv = z[(size_t)bq * DDIM * HW + (size_t)lane * HW + hq * 64 + wq];
        const float p = mul_rn(xv, xv);
        float r = 0.f;
        for (int i = 0; i < 8; ++i) {
            const float t = __shfl(p, (i << 3) + (lane & 7), 64);
            r = add_rn(r, t);
        }
        const float s01 = add_rn(r, __shfl_xor(r, 1, 64));
        const float s03 = add_rn(s01, __shfl_xor(s01, 2, 64));
        const float s07 = add_rn(s03, __shfl_xor(s03, 4, 64));
        const float x2s = __shfl(s07, 0, 64);

        float acc[16];
#pragma unroll
        for (int j = 0; j < 16; ++j) acc[j] = 0.f;
        for (int d = 0; d < DDIM; ++d) {
            const float xd = __shfl(xv, d, 64);
            const float* ecol = embT + (size_t)d * KCODES + lane;
#pragma unroll
            for (int j = 0; j < 16; ++j)
                acc[j] = fmaf(ecol[64 * j], xd, acc[j]);
        }
        float bv = 1e30f;
        int bk = KCODES;
#pragma unroll
        for (int j = 0; j < 16; ++j) {
            const int kk = lane + 64 * j;
            const float s  = add_rn(x2s, w2[kk]);
            const float dv = sub2_rn(s, acc[j]);
            if (dv < bv) { bv = dv; bk = kk; }
        }
        for (int off = 32; off > 0; off >>= 1) {
            const float ov = __shfl_xor(bv, off, 64);
            const int   ok = __shfl_xor(bk, off, 64);
            if (ov < bv || (ov == bv && ok < bk)) { bv = ov; bk = ok; }
        }
        if (lane == src) k1 = bk;
    }
    if (lane < 32) k1s[wid * 32 + lane] = (unsigned)k1;
    __syncthreads();

    const int part = blockIdx.x & pmask;
    if (tid < 256) {
        const unsigned myk = k1s[tid];
        out[OFF_IDX + (size_t)(nb + tid)] = (float)myk;
        atomicAdd(&cnt_p[part * KCODES + myk], 1u);
    }

    float ls = 0.f;
    {
        const int h = lane >> 4, w4 = (lane & 15) * 4;
        const int row = h * 64 + w4;
#pragma unroll 2
        for (int it = 0; it < 8; ++it) {
            const int d = wid + 8 * it;
            float4 q;
            float* qp = (float*)&q;
#pragma unroll
            for (int j = 0; j < 4; ++j) {
                const unsigned k = k1s[row + j];
                const float wv = emb[(size_t)k * DDIM + d];
                qp[j] = wv;
                const float diff = bfu2f(sxt[d][row + j]) - wv;
                ls = fmaf(diff, diff, ls);
            }
            *(float4*)&out[((size_t)(b * 64 + d)) * HW + (hb + h) * 64 + w4] = q;
        }
    }
#pragma unroll
    for (int off = 32; off > 0; off >>= 1) ls += __shfl_down(ls, off, 64);
    if (lane == 0) redl[wid] = ls;
    __syncthreads();
    if (tid == 0) {
        float t = 0.f;
#pragma unroll
        for (int i = 0; i < 8; ++i) t += redl[i];
        lossb[blockIdx.x] = t;
    }
    {
        float* ep = esum_p + (size_t)part * 65536;
        for (int r = 0; r < 32; ++r) {
            const int row = wid * 32 + r;
            atomicAdd(&ep[(size_t)k1s[row] * DDIM + lane], bfu2f(sxt[lane][row]));
        }
    }
}

__global__ __launch_bounds__(1024) void finalize1_kernel(
        const float* __restrict__ cs, float* __restrict__ out,
        const unsigned* __restrict__ cnt_p, const float* __restrict__ lossb,
        float* __restrict__ smoothed, int P) {
    const int k = threadIdx.x;
    unsigned c = 0;
    for (int p = 0; p < P; ++p) c += cnt_p[p * KCODES + k];
    const float ncs = fmaf(0.01f, (float)c, 0.99f * cs[k]);

    __shared__ float red[1024];
    red[k] = ncs;
    __syncthreads();
    for (int s = 512; s > 0; s >>= 1) {
        if (k < s) red[k] += red[k + s];
        __syncthreads();
    }
    const float nn = red[0];
    smoothed[k] = (ncs + 1e-5f) / (nn + 1024.f * 1e-5f) * nn;
    out[OFF_NCS + (size_t)k] = ncs;

    __syncthreads();
    red[k] = (k < 512) ? lossb[k] : 0.f;
    __syncthreads();
    for (int s = 512; s > 0; s >>= 1) {
        if (k < s) red[k] += red[k + s];
        __syncthreads();
    }
    if (k == 0) out[OFF_LOSS] = 0.25f * red[0] / 8388608.f;
}

__global__ __launch_bounds__(256) void finalize2_kernel(
        const float* __restrict__ eavg, float* __restrict__ out,
        const float* __restrict__ esum_p, const float* __restrict__ smoothed,
        int P) {
    const int e = blockIdx.x * 256 + threadIdx.x;
    float s = 0.f;
    for (int p = 0; p < P; ++p) s += esum_p[(size_t)p * 65536 + e];
    const float ea = fmaf(0.01f, s, 0.99f * eavg[e]);
    out[OFF_EAVG + (size_t)e] = ea;
    out[OFF_EMB  + (size_t)e] = ea / smoothed[e >> 6];
}

// =========================================================================

extern "C" void kernel_launch(void* const* d_in, const int* in_sizes, int n_in,
                              void* d_out, int out_size, void* d_ws, size_t ws_size,
                              hipStream_t stream) {
    const float* z    = (const float*)d_in[0];
    const float* emb  = (const float*)d_in[1];
    const float* cs   = (const float*)d_in[2];
    const float* eavg = (const float*)d_in[3];
    float* out = (float*)d_out;

    unsigned short* wh = (unsigned short*)((char*)d_out + SCR_B0);
    unsigned short* wl = (unsigned short*)((char*)d_out + SCR_WLO);
    float*          w2 = (float*)((char*)d_out + SCR_W2O);
    char* ws = (char*)d_ws;

    if (ws_size >= FWS_TOTAL) {
        unsigned short*     xT   = (unsigned short*)ws;
        unsigned short*     kidx = (unsigned short*)(ws + FWS_KSCR);
        float*              scs  = (float*)(ws + FWS_SCS);
        unsigned*           list = (unsigned*)(ws + FWS_LIST);
        unsigned long long* rmin = (unsigned long long*)(ws + FWS_RMIN);
        unsigned*           cntr = (unsigned*)(ws + FWS_CNTR);
        float*              lossA = (float*)(ws + FWS_LOSSA);

        (void)hipMemsetAsync(ws + FWS_CNTR, 0, 8, stream);
        prep_kernel<<<16, 256, 0, stream>>>(emb, cs, wh, wl, w2, nullptr, scs);
        score2_kernel<<<NROWS / 512, 512, 0, stream>>>(
            z, emb, wh, wl, w2, out, xT, kidx, list, rmin, cntr);
        rescanb_kernel<<<256, 256, 0, stream>>>(z, emb, w2, list, cntr, rmin);
        fix_kernel<<<LCAP / 4, 256, 0, stream>>>(list, rmin, cntr, emb, kidx, out);
        gatherfin_kernel<<<KCODES, 256, 0, stream>>>(
            kidx, xT, emb, cs, eavg, w2, scs, out, lossA);
        lossfin_kernel<<<1, 64, 0, stream>>>(lossA, out);
    } else {
        int P = 1;
        for (int p = 16; p >= 1; p >>= 1)
            if (ws_size >= WSO_ESUM + (size_t)p * 262144ull) { P = p; break; }

        float*    embT   = (float*)ws;
        unsigned* kscr   = (unsigned*)(ws + WSO_KSCR);
        float*    lossb  = (float*)(ws + WSO_LOSSB);
        float*    smooth = (float*)(ws + WSO_SMOOTH);
        unsigned* cnt_p  = (unsigned*)(ws + WSO_CNT);
        float*    esum_p = (float*)(ws + WSO_ESUM);

        (void)hipMemsetAsync(ws + WSO_CNT, 0, 65536 + (size_t)P * 262144ull, stream);
        prep_kernel<<<16, 256, 0, stream>>>(emb, cs, wh, wl, w2, embT,
                                            (float*)(ws + WSO_SMOOTH));
        score_kernel<<<NROWS / 256, 512, 0, stream>>>(z, wh, wl, w2, kscr);
        output_kernel<<<NROWS / 256, 512, 0, stream>>>(
            z, emb, embT, w2, out, kscr, esum_p, cnt_p, lossb, P - 1);
        finalize1_kernel<<<1, 1024, 0, stream>>>(cs, out, cnt_p, lossb, smooth, P);
        finalize2_kernel<<<256, 256, 0, stream>>>(eavg, out, esum_p, smooth, P);
    }
}